// Round 4
// baseline (171.222 us; speedup 1.0000x reference)
//
#include <hip/hip_runtime.h>
#include <hip/hip_bf16.h>

// Problem constants (fixed by the reference)
#define NUM_LOC   100000
#define EMB_D     256
#define NCLUST    50
#define NTOK      12800   // B*L = 64*200
#define OUT_D     384     // 256 + 128
#define TPW       4       // tokens per wave

// One wave (64 lanes) per TPW tokens; 4 waves (256 threads) per block.
// grid = NTOK / (4*TPW) = 800 blocks.
__global__ __launch_bounds__(256)
void hle_kernel(const int*   __restrict__ loc_ids,        // (B,L) int32
                const float* __restrict__ loc_table,      // (NUM_LOC,256) f32
                const float* __restrict__ cluster_table,  // (50,128) f32
                const float* __restrict__ W_lc,           // (50,NUM_LOC) f32
                const float* __restrict__ b_lc,           // (50,) f32
                float*       __restrict__ out)            // f32 (NTOK,384)
{
    // cluster_table staged in LDS: 50*128*4 = 25.6 KB
    __shared__ float s_ct[NCLUST * 128];

    const int tid = threadIdx.x;

    // --- stage cluster_table into LDS as float4 (1600 float4 / 256 threads) ---
    {
        const float4* src = (const float4*)cluster_table;
        float4* dst = (float4*)s_ct;
        for (int i = tid; i < NCLUST * 32; i += 256)
            dst[i] = src[i];
    }
    __syncthreads();

    const int wave = tid >> 6;
    const int lane = tid & 63;
    const int t0   = (blockIdx.x * 4 + wave) * TPW;   // NTOK divisible by 16

    // hoisted per-wave invariants
    const float bias = (lane < NCLUST) ? b_lc[lane] : 0.0f;
    const float* wrow = W_lc + (size_t)lane * NUM_LOC;  // only deref'd when lane<50

    // --- load the 4 token ids ---
    int ids[TPW];
    #pragma unroll
    for (int t = 0; t < TPW; ++t) ids[t] = loc_ids[t0 + t];

    // --- issue all fine-row gathers + logit gathers up front (max MLP) ---
    float4 fine[TPW];
    float  logit[TPW];
    #pragma unroll
    for (int t = 0; t < TPW; ++t) {
        fine[t] = ((const float4*)(loc_table + (size_t)ids[t] * EMB_D))[lane];
        if (lane < NCLUST) logit[t] = wrow[ids[t]] + bias;
        else               logit[t] = -INFINITY;
    }

    // --- 4 independent wave-wide softmaxes (shuffle chains interleave) ---
    float w[TPW];
    #pragma unroll
    for (int t = 0; t < TPW; ++t) {
        float m = logit[t];
        #pragma unroll
        for (int off = 32; off > 0; off >>= 1)
            m = fmaxf(m, __shfl_xor(m, off, 64));
        float e = (lane < NCLUST) ? __expf(logit[t] - m) : 0.0f;
        float s = e;
        #pragma unroll
        for (int off = 32; off > 0; off >>= 1)
            s += __shfl_xor(s, off, 64);
        w[t] = e / s;
    }

    // --- coarse: one ds_read_b64 per cluster serves all 4 tokens ---
    float acc0[TPW] = {0.f, 0.f, 0.f, 0.f};
    float acc1[TPW] = {0.f, 0.f, 0.f, 0.f};
    const float2* ct2 = (const float2*)s_ct;
    #pragma unroll
    for (int c = 0; c < NCLUST; ++c) {
        float2 v = ct2[c * 64 + lane];         // 2-way bank mode (free)
        #pragma unroll
        for (int t = 0; t < TPW; ++t) {
            float wc = __shfl(w[t], c, 64);    // readlane broadcast
            acc0[t] = fmaf(wc, v.x, acc0[t]);
            acc1[t] = fmaf(wc, v.y, acc1[t]);
        }
    }

    // --- write 4 output rows: [fine(256) | coarse(128)] as f32 ---
    #pragma unroll
    for (int t = 0; t < TPW; ++t) {
        float* orow = out + (size_t)(t0 + t) * OUT_D;
        ((float4*)orow)[lane] = fine[t];                       // coalesced 1 KB
        ((float2*)(orow + EMB_D))[lane] = make_float2(acc0[t], acc1[t]);
    }
}

extern "C" void kernel_launch(void* const* d_in, const int* in_sizes, int n_in,
                              void* d_out, int out_size, void* d_ws, size_t ws_size,
                              hipStream_t stream) {
    const int*   loc_ids       = (const int*)d_in[0];
    const float* loc_table     = (const float*)d_in[1];
    const float* cluster_table = (const float*)d_in[2];
    const float* W_lc          = (const float*)d_in[3];
    const float* b_lc          = (const float*)d_in[4];
    float*       out           = (float*)d_out;

    hle_kernel<<<NTOK / (4 * TPW), 256, 0, stream>>>(loc_ids, loc_table, cluster_table,
                                                     W_lc, b_lc, out);
}